// Round 1
// baseline (579.345 us; speedup 1.0000x reference)
//
#include <hip/hip_runtime.h>

using bf16x8 = __attribute__((ext_vector_type(8))) short;
using f32x4  = __attribute__((ext_vector_type(4))) float;
using u16 = unsigned short;
using u32 = unsigned int;

// ---------- helpers ----------
__device__ __forceinline__ u16 f2bf(float f) {          // RNE float->bf16
  u32 u = __float_as_uint(f);
  u += 0x7fffu + ((u >> 16) & 1u);
  return (u16)(u >> 16);
}
__device__ __forceinline__ float bf2f(u16 h) {
  return __uint_as_float(((u32)h) << 16);
}
__device__ __forceinline__ uint4 pack8(const u16* h) {
  uint4 r;
  r.x = (u32)h[0] | ((u32)h[1] << 16);
  r.y = (u32)h[2] | ((u32)h[3] << 16);
  r.z = (u32)h[4] | ((u32)h[5] << 16);
  r.w = (u32)h[6] | ((u32)h[7] << 16);
  return r;
}
__device__ __forceinline__ float gelu_tanh(float x) {   // JAX approximate=True
  float u = 0.7978845608028654f * (x + 0.044715f * x * x * x);
  return 0.5f * x * (1.0f + tanhf(u));
}
__device__ __forceinline__ void gload16(const void* g, void* l) {
  __builtin_amdgcn_global_load_lds(
      (const __attribute__((address_space(1))) void*)g,
      (__attribute__((address_space(3))) void*)l, 16, 0, 0);
}

// ---------- weight transpose: [R,C] f32 -> [C,R] bf16 (hi, optional lo) ----------
__global__ __launch_bounds__(256) void transpose_split_kernel(
    const float* __restrict__ in, u16* __restrict__ outH, u16* __restrict__ outL,
    int R, int C)
{
  __shared__ float t[32][33];
  const int lx = threadIdx.x & 31, ly = threadIdx.x >> 5;
  const int c0 = blockIdx.x << 5, r0 = blockIdx.y << 5;
  for (int i = ly; i < 32; i += 8)
    t[i][lx] = in[(long)(r0 + i) * C + c0 + lx];
  __syncthreads();
  for (int i = ly; i < 32; i += 8) {
    float v = t[lx][i];
    long o = (long)(c0 + i) * R + r0 + lx;
    u16 h = f2bf(v);
    outH[o] = h;
    if (outL) outL[o] = f2bf(v - bf2f(h));
  }
}

// ---------- LayerNorm over rows of 512 f32, out bf16 hi (+ optional lo) ----------
__global__ __launch_bounds__(256) void ln_split_kernel(
    const float* __restrict__ x, const float* __restrict__ gamma,
    const float* __restrict__ beta, u16* __restrict__ outH, u16* __restrict__ outL)
{
  const int row  = (blockIdx.x << 2) + (threadIdx.x >> 6);
  const int lane = threadIdx.x & 63;
  const float* xr = x + (long)row * 512 + lane * 8;
  float v[8];
  *(float4*)&v[0] = *(const float4*)xr;
  *(float4*)&v[4] = *(const float4*)(xr + 4);
  float s = 0.f;
#pragma unroll
  for (int j = 0; j < 8; ++j) s += v[j];
#pragma unroll
  for (int o = 32; o; o >>= 1) s += __shfl_xor(s, o);
  const float mu = s * (1.0f / 512.0f);
  float q = 0.f;
#pragma unroll
  for (int j = 0; j < 8; ++j) { float d = v[j] - mu; q += d * d; }
#pragma unroll
  for (int o = 32; o; o >>= 1) q += __shfl_xor(q, o);
  const float rs = rsqrtf(q * (1.0f / 512.0f) + 1e-5f);
  float gv[8], bv[8];
  *(float4*)&gv[0] = *(const float4*)(gamma + lane * 8);
  *(float4*)&gv[4] = *(const float4*)(gamma + lane * 8 + 4);
  *(float4*)&bv[0] = *(const float4*)(beta + lane * 8);
  *(float4*)&bv[4] = *(const float4*)(beta + lane * 8 + 4);
  u16 hs[8], ls[8];
#pragma unroll
  for (int j = 0; j < 8; ++j) {
    float y = (v[j] - mu) * rs * gv[j] + bv[j];
    hs[j] = f2bf(y);
    ls[j] = f2bf(y - bf2f(hs[j]));
  }
  *(uint4*)(outH + (long)row * 512 + lane * 8) = pack8(hs);
  if (outL) *(uint4*)(outL + (long)row * 512 + lane * 8) = pack8(ls);
}

// ---------- row softmax over 512 f32 -> bf16 ----------
__global__ __launch_bounds__(256) void softmax_kernel(
    const float* __restrict__ scores, u16* __restrict__ attn)
{
  const int row  = (blockIdx.x << 2) + (threadIdx.x >> 6);
  const int lane = threadIdx.x & 63;
  const float* sr = scores + (long)row * 512 + lane * 8;
  float v[8];
  *(float4*)&v[0] = *(const float4*)sr;
  *(float4*)&v[4] = *(const float4*)(sr + 4);
  float m = v[0];
#pragma unroll
  for (int j = 1; j < 8; ++j) m = fmaxf(m, v[j]);
#pragma unroll
  for (int o = 32; o; o >>= 1) m = fmaxf(m, __shfl_xor(m, o));
  float e[8], s = 0.f;
#pragma unroll
  for (int j = 0; j < 8; ++j) { e[j] = __expf(v[j] - m); s += e[j]; }
#pragma unroll
  for (int o = 32; o; o >>= 1) s += __shfl_xor(s, o);
  const float inv = 1.0f / s;
  u16 h[8];
#pragma unroll
  for (int j = 0; j < 8; ++j) h[j] = f2bf(e[j] * inv);
  *(uint4*)(attn + (long)row * 512 + lane * 8) = pack8(h);
}

// ---------- NT GEMM: C[m,n] = sum_k A[m,k]*B[n,k], 128x128 tile, BK=32 ----------
// SPLIT=1: A,B given as hi+lo bf16 pairs; 3-pass accumulation (AhBh+AlBh+AhBl).
// EPI: 0 vx=|.|  1 split-write  2 |.| f32  3 resid+acc  4 gelu(acc+bias)  5 resid+acc+bias
template<int SPLIT, int EPI>
__global__ __launch_bounds__(256, 2) void gemm_nt(
    const u16* __restrict__ Ah, const u16* __restrict__ Al,
    const u16* __restrict__ Bh, const u16* __restrict__ Bl,
    int N, int K, long strideA, long strideB, long strideC,
    float* __restrict__ outF, u16* __restrict__ outU, u16* __restrict__ outU2,
    const float* __restrict__ resid, const float* __restrict__ bias)
{
  __shared__ __align__(16) u16 sm[(SPLIT ? 4 : 2) * 4096];
  u16* sAh = sm;
  u16* sBh = sm + 4096;
  u16* sAl = sm + 8192;
  u16* sBl = sm + 12288;

  const int tid  = threadIdx.x;
  const int wave = tid >> 6, lane = tid & 63;
  const int b    = blockIdx.z;
  const char* pA  = (const char*)(Ah + (long)b * strideA + (long)blockIdx.y * 128 * K);
  const char* pB  = (const char*)(Bh + (long)b * strideB + (long)blockIdx.x * 128 * K);
  const char* pAl = SPLIT ? (const char*)(Al + (long)b * strideA + (long)blockIdx.y * 128 * K) : nullptr;
  const char* pBl = SPLIT ? (const char*)(Bl + (long)b * strideB + (long)blockIdx.x * 128 * K) : nullptr;

  f32x4 acc[4][4];
#pragma unroll
  for (int i = 0; i < 4; ++i)
#pragma unroll
    for (int j = 0; j < 4; ++j) acc[i][j] = (f32x4){0.f, 0.f, 0.f, 0.f};

  const int wr = wave >> 1, wc = wave & 1;
  const int lrow = lane & 15;
  const int kofs = (lane >> 4) << 3;   // k element offset within BK=32
  const int srow = lane >> 2;          // staging: row within 16-row chunk
  const int scolb = (lane & 3) << 4;   // staging: byte col within 64B row

  for (int k0 = 0; k0 < K; k0 += 32) {
    __syncthreads();
#pragma unroll
    for (int r = 0; r < 2; ++r) {
      const int chunk = (r << 2) + wave;
      const int row = (chunk << 4) + srow;
      const long gb = (long)row * (K << 1) + ((long)k0 << 1) + scolb;
      gload16(pA + gb, sAh + (chunk << 9));
      gload16(pB + gb, sBh + (chunk << 9));
      if (SPLIT) {
        gload16(pAl + gb, sAl + (chunk << 9));
        gload16(pBl + gb, sBl + (chunk << 9));
      }
    }
    __syncthreads();
    bf16x8 af[4], bfr[4];
#pragma unroll
    for (int mi = 0; mi < 4; ++mi)
      af[mi] = *(const bf16x8*)(sAh + (((wr << 6) + (mi << 4) + lrow) << 5) + kofs);
#pragma unroll
    for (int ni = 0; ni < 4; ++ni)
      bfr[ni] = *(const bf16x8*)(sBh + (((wc << 6) + (ni << 4) + lrow) << 5) + kofs);
#pragma unroll
    for (int mi = 0; mi < 4; ++mi)
#pragma unroll
      for (int ni = 0; ni < 4; ++ni)
        acc[mi][ni] = __builtin_amdgcn_mfma_f32_16x16x32_bf16(af[mi], bfr[ni], acc[mi][ni], 0, 0, 0);
    if (SPLIT) {
      bf16x8 xf[4];
#pragma unroll
      for (int mi = 0; mi < 4; ++mi)
        xf[mi] = *(const bf16x8*)(sAl + (((wr << 6) + (mi << 4) + lrow) << 5) + kofs);
#pragma unroll
      for (int mi = 0; mi < 4; ++mi)
#pragma unroll
        for (int ni = 0; ni < 4; ++ni)
          acc[mi][ni] = __builtin_amdgcn_mfma_f32_16x16x32_bf16(xf[mi], bfr[ni], acc[mi][ni], 0, 0, 0);
#pragma unroll
      for (int ni = 0; ni < 4; ++ni)
        xf[ni] = *(const bf16x8*)(sBl + (((wc << 6) + (ni << 4) + lrow) << 5) + kofs);
#pragma unroll
      for (int mi = 0; mi < 4; ++mi)
#pragma unroll
        for (int ni = 0; ni < 4; ++ni)
          acc[mi][ni] = __builtin_amdgcn_mfma_f32_16x16x32_bf16(af[mi], xf[ni], acc[mi][ni], 0, 0, 0);
    }
  }

  const long cb = (long)b * strideC;
  const int m0 = blockIdx.y * 128 + (wr << 6) + ((lane >> 4) << 2);
  const int n0 = blockIdx.x * 128 + (wc << 6) + lrow;
#pragma unroll
  for (int mi = 0; mi < 4; ++mi)
#pragma unroll
    for (int ni = 0; ni < 4; ++ni)
#pragma unroll
      for (int r = 0; r < 4; ++r) {
        const int m = m0 + (mi << 4) + r;
        const int n = n0 + (ni << 4);
        const long idx = cb + (long)m * N + n;
        const float v = acc[mi][ni][r];
        if (EPI == 0) {
          outU[idx] = f2bf(sqrtf(v * v + 1e-8f));
        } else if (EPI == 1) {
          u16 h = f2bf(v);
          outU[idx] = h;
          outU2[idx] = f2bf(v - bf2f(h));
        } else if (EPI == 2) {
          outF[idx] = sqrtf(v * v + 1e-8f);
        } else if (EPI == 3) {
          outF[idx] = resid[idx] + v;
        } else if (EPI == 4) {
          outU[idx] = f2bf(gelu_tanh(v + bias[n]));
        } else {
          outF[idx] = resid[idx] + v + bias[n];
        }
      }
}

// ---------- launch ----------
extern "C" void kernel_launch(void* const* d_in, const int* in_sizes, int n_in,
                              void* d_out, int out_size, void* d_ws, size_t ws_size,
                              hipStream_t stream)
{
  const float* x   = (const float*)d_in[0];
  const float* g1  = (const float*)d_in[1];
  const float* be1 = (const float*)d_in[2];
  const float* Wv  = (const float*)d_in[3];
  const float* Ww  = (const float*)d_in[4];
  const float* g2  = (const float*)d_in[5];
  const float* be2 = (const float*)d_in[6];
  const float* W1  = (const float*)d_in[7];
  const float* b1  = (const float*)d_in[8];
  const float* W2  = (const float*)d_in[9];
  const float* b2  = (const float*)d_in[10];
  float* out = (float*)d_out;

  char* ws = (char*)d_ws;
  // B=64, T=E=512, H=2048, M=B*T=32768
  u16* inp_hi  = (u16*)(ws + 0);            // 32MB, later h_mid part
  u16* inp_lo  = (u16*)(ws + 33554432);     // 32MB, later attn, then h_mid part
  u16* proj_hi = (u16*)(ws + 67108864);     // 32MB, later h_mid part
  u16* proj_lo = (u16*)(ws + 100663296);    // 32MB, later h_mid part
  u16* attn    = inp_lo;                    // alias (inp_lo dead after scores GEMM)
  u16* h_mid   = (u16*)(ws + 0);            // alias, 128MB (dead: inp/proj/attn)
  float* scores= (float*)(ws + 134217728);  // 64MB
  u16* vx      = (u16*)(ws + 201326592);    // 32MB
  u16* h_in    = vx;                        // alias (vx dead after t-GEMM)
  u16* WvT     = (u16*)(ws + 234881024);
  u16* WwTh    = (u16*)(ws + 235405312);
  u16* WwTl    = (u16*)(ws + 235929600);
  u16* W1T     = (u16*)(ws + 236453888);
  u16* W2T     = (u16*)(ws + 238551040);
  // total ws needed: 240648192 bytes

  // weight transposes (f32 -> bf16, K-contiguous for NT GEMM)
  transpose_split_kernel<<<dim3(16, 16), 256, 0, stream>>>(Wv, WvT, nullptr, 512, 512);
  transpose_split_kernel<<<dim3(16, 16), 256, 0, stream>>>(Ww, WwTh, WwTl, 512, 512);
  transpose_split_kernel<<<dim3(64, 16), 256, 0, stream>>>(W1, W1T, nullptr, 512, 2048);
  transpose_split_kernel<<<dim3(16, 64), 256, 0, stream>>>(W2, W2T, nullptr, 2048, 512);

  // LN1: x -> inp hi/lo (split for logits precision)
  ln_split_kernel<<<8192, 256, 0, stream>>>(x, g1, be1, inp_hi, inp_lo);

  // vx = sqrt((inp@Wv)^2 + eps)   [M=32768, N=512, K=512]
  gemm_nt<0, 0><<<dim3(4, 256, 1), 256, 0, stream>>>(
      inp_hi, nullptr, WvT, nullptr, 512, 512, 0, 0, 0,
      nullptr, vx, nullptr, nullptr, nullptr);

  // proj = inp@Ww (split 3-pass), write hi/lo
  gemm_nt<1, 1><<<dim3(4, 256, 1), 256, 0, stream>>>(
      inp_hi, inp_lo, WwTh, WwTl, 512, 512, 0, 0, 0,
      nullptr, proj_hi, proj_lo, nullptr, nullptr);

  // scores[b,i,j] = sqrt((proj_i . inp_j)^2 + eps) (split 3-pass), batched 64
  gemm_nt<1, 2><<<dim3(4, 4, 64), 256, 0, stream>>>(
      proj_hi, proj_lo, inp_hi, inp_lo, 512, 512, 262144, 262144, 262144,
      scores, nullptr, nullptr, nullptr, nullptr);

  // softmax rows -> attn bf16
  softmax_kernel<<<8192, 256, 0, stream>>>(scores, attn);

  // x1 = x + attn@vx^T  -> d_out (batched)
  gemm_nt<0, 3><<<dim3(4, 4, 64), 256, 0, stream>>>(
      attn, nullptr, vx, nullptr, 512, 512, 262144, 262144, 262144,
      out, nullptr, nullptr, x, nullptr);

  // LN2: x1 -> h_in (bf16 hi only)
  ln_split_kernel<<<8192, 256, 0, stream>>>(out, g2, be2, h_in, nullptr);

  // h_mid = gelu(h_in@W1 + b1)   [M=32768, N=2048, K=512]
  gemm_nt<0, 4><<<dim3(16, 256, 1), 256, 0, stream>>>(
      h_in, nullptr, W1T, nullptr, 2048, 512, 0, 0, 0,
      nullptr, h_mid, nullptr, nullptr, b1);

  // out = x1 + h_mid@W2 + b2     [M=32768, N=512, K=2048]
  gemm_nt<0, 5><<<dim3(4, 256, 1), 256, 0, stream>>>(
      h_mid, nullptr, W2T, nullptr, 512, 2048, 0, 0, 0,
      out, nullptr, nullptr, out, b2);
}

// Round 2
// 515.092 us; speedup vs baseline: 1.1247x; 1.1247x over previous
//
#include <hip/hip_runtime.h>

using bf16x8 = __attribute__((ext_vector_type(8))) short;
using f32x4  = __attribute__((ext_vector_type(4))) float;
using u16 = unsigned short;
using u32 = unsigned int;

// ---------- helpers ----------
__device__ __forceinline__ u16 f2bf(float f) {          // RNE float->bf16
  u32 u = __float_as_uint(f);
  u += 0x7fffu + ((u >> 16) & 1u);
  return (u16)(u >> 16);
}
__device__ __forceinline__ float bf2f(u16 h) {
  return __uint_as_float(((u32)h) << 16);
}
__device__ __forceinline__ uint4 pack8(const u16* h) {
  uint4 r;
  r.x = (u32)h[0] | ((u32)h[1] << 16);
  r.y = (u32)h[2] | ((u32)h[3] << 16);
  r.z = (u32)h[4] | ((u32)h[5] << 16);
  r.w = (u32)h[6] | ((u32)h[7] << 16);
  return r;
}
__device__ __forceinline__ float gelu_tanh(float x) {   // JAX approximate=True
  float u = 0.7978845608028654f * (x + 0.044715f * x * x * x);
  return 0.5f * x * (1.0f + tanhf(u));
}
__device__ __forceinline__ void gload16(const void* g, void* l) {
  __builtin_amdgcn_global_load_lds(
      (const __attribute__((address_space(1))) void*)g,
      (__attribute__((address_space(3))) void*)l, 16, 0, 0);
}

#define BAR() __builtin_amdgcn_s_barrier()
#define LGKM0() do { asm volatile("s_waitcnt lgkmcnt(0)" ::: "memory"); \
                     __builtin_amdgcn_sched_barrier(0); } while (0)
#define VMW(n)  do { asm volatile("s_waitcnt vmcnt(" #n ")" ::: "memory"); \
                     __builtin_amdgcn_sched_barrier(0); } while (0)

// ---------- weight transpose: [R,C] f32 -> [C,R] bf16 (hi, optional lo) ----------
__global__ __launch_bounds__(256) void transpose_split_kernel(
    const float* __restrict__ in, u16* __restrict__ outH, u16* __restrict__ outL,
    int R, int C)
{
  __shared__ float t[32][33];
  const int lx = threadIdx.x & 31, ly = threadIdx.x >> 5;
  const int c0 = blockIdx.x << 5, r0 = blockIdx.y << 5;
  for (int i = ly; i < 32; i += 8)
    t[i][lx] = in[(long)(r0 + i) * C + c0 + lx];
  __syncthreads();
  for (int i = ly; i < 32; i += 8) {
    float v = t[lx][i];
    long o = (long)(c0 + i) * R + r0 + lx;
    u16 h = f2bf(v);
    outH[o] = h;
    if (outL) outL[o] = f2bf(v - bf2f(h));
  }
}

// ---------- LayerNorm over rows of 512 f32, out bf16 hi (+ optional lo) ----------
__global__ __launch_bounds__(256) void ln_split_kernel(
    const float* __restrict__ x, const float* __restrict__ gamma,
    const float* __restrict__ beta, u16* __restrict__ outH, u16* __restrict__ outL)
{
  const int row  = (blockIdx.x << 2) + (threadIdx.x >> 6);
  const int lane = threadIdx.x & 63;
  const float* xr = x + (long)row * 512 + lane * 8;
  float v[8];
  *(float4*)&v[0] = *(const float4*)xr;
  *(float4*)&v[4] = *(const float4*)(xr + 4);
  float s = 0.f;
#pragma unroll
  for (int j = 0; j < 8; ++j) s += v[j];
#pragma unroll
  for (int o = 32; o; o >>= 1) s += __shfl_xor(s, o);
  const float mu = s * (1.0f / 512.0f);
  float q = 0.f;
#pragma unroll
  for (int j = 0; j < 8; ++j) { float d = v[j] - mu; q += d * d; }
#pragma unroll
  for (int o = 32; o; o >>= 1) q += __shfl_xor(q, o);
  const float rs = rsqrtf(q * (1.0f / 512.0f) + 1e-5f);
  float gv[8], bv[8];
  *(float4*)&gv[0] = *(const float4*)(gamma + lane * 8);
  *(float4*)&gv[4] = *(const float4*)(gamma + lane * 8 + 4);
  *(float4*)&bv[0] = *(const float4*)(beta + lane * 8);
  *(float4*)&bv[4] = *(const float4*)(beta + lane * 8 + 4);
  u16 hs[8], ls[8];
#pragma unroll
  for (int j = 0; j < 8; ++j) {
    float y = (v[j] - mu) * rs * gv[j] + bv[j];
    hs[j] = f2bf(y);
    ls[j] = f2bf(y - bf2f(hs[j]));
  }
  *(uint4*)(outH + (long)row * 512 + lane * 8) = pack8(hs);
  if (outL) *(uint4*)(outL + (long)row * 512 + lane * 8) = pack8(ls);
}

// ---------- row softmax over 512 f32 -> bf16 ----------
__global__ __launch_bounds__(256) void softmax_kernel(
    const float* __restrict__ scores, u16* __restrict__ attn)
{
  const int row  = (blockIdx.x << 2) + (threadIdx.x >> 6);
  const int lane = threadIdx.x & 63;
  const float* sr = scores + (long)row * 512 + lane * 8;
  float v[8];
  *(float4*)&v[0] = *(const float4*)sr;
  *(float4*)&v[4] = *(const float4*)(sr + 4);
  float m = v[0];
#pragma unroll
  for (int j = 1; j < 8; ++j) m = fmaxf(m, v[j]);
#pragma unroll
  for (int o = 32; o; o >>= 1) m = fmaxf(m, __shfl_xor(m, o));
  float e[8], s = 0.f;
#pragma unroll
  for (int j = 0; j < 8; ++j) { e[j] = __expf(v[j] - m); s += e[j]; }
#pragma unroll
  for (int o = 32; o; o >>= 1) s += __shfl_xor(s, o);
  const float inv = 1.0f / s;
  u16 h[8];
#pragma unroll
  for (int j = 0; j < 8; ++j) h[j] = f2bf(e[j] * inv);
  *(uint4*)(attn + (long)row * 512 + lane * 8) = pack8(h);
}

// ---------- 256x256 8-wave 4-phase NT GEMM, BK=64 ----------
// C[m,n] = sum_k A[m,k]*B[n,k].  K split into NT tiles of 64; tile t reads
// part pointer (t>>3) of each operand (enables hi/lo K-concatenation for the
// precision-split GEMMs without materializing the concat).
// Schedule per K-tile (buffers by t&1, staging t+2 into the SAME buffer):
//   P1: ds_read A[mh0](8xb128)+B[nh0](4); BAR; lgkm0; 16 MFMA; BAR
//   P2: ds_read B[nh1](4);                BAR; lgkm0; 16 MFMA; BAR
//        (all B reads of this tile now complete -> B region dead)
//   P3: ds_read A[mh1](8); stage t+2 B halves; BAR; lgkm0; 16 MFMA; BAR
//        (all A reads complete -> A region dead)
//   P4: stage t+2 A halves; BAR; lgkm0; 16 MFMA; vmcnt(8); BAR
// vmcnt(8) = allow the 8 loads just issued (t+2), force t+1 landed. Drains to
// vmcnt(0) only in the last two iterations.
// LDS swizzle: linear global_load_lds dest + inverse-swizzled global source +
// swizzled ds_read (slot ^= row&7 within each 128B row) -> 2-way conflicts.
// EPI: 0 bf16 |.|; 1 split hi/lo write; 2 f32 sqrt(v^2+eps); 3 resid+v;
//      4 gelu(v+bias) bf16; 5 resid+v+bias.
template<int EPI>
__global__ __launch_bounds__(512, 2) void gemm8(
    const char* A0, const char* A1, const char* A2, const char* A3,
    const char* B0, const char* B1, const char* B2, const char* B3,
    int N, int NT, int ldAb, int ldBb,
    long sAb, long sBb, long sC,
    float* __restrict__ outF, u16* __restrict__ outU, u16* __restrict__ outU2,
    const float* __restrict__ resid, const float* __restrict__ bias)
{
  __shared__ __align__(16) char lds[131072];
  const int tid = threadIdx.x;
  const int w = tid >> 6, l = tid & 63;
  const int wm = w >> 2, wn = w & 3;
  const long blockM = (long)blockIdx.y * 256;
  const long blockN = (long)blockIdx.x * 256;
  const long za = (long)blockIdx.z * sAb;
  const long zb = (long)blockIdx.z * sBb;
  const char* a0 = A0 + za; const char* a1 = A1 + za;
  const char* a2 = A2 + za; const char* a3 = A3 + za;
  const char* b0 = B0 + zb; const char* b1 = B1 + zb;
  const char* b2 = B2 + zb; const char* b3 = B3 + zb;

  auto partA = [&](int t) { return t < 8 ? a0 : t < 16 ? a1 : t < 24 ? a2 : a3; };
  auto partB = [&](int t) { return t < 8 ? b0 : t < 16 ? b1 : t < 24 ? b2 : b3; };

  // staging: thread tid covers rows (w*8 + l>>3) and +64 of a 128-row half;
  // source slot = destSlot ^ (row&7) = (l&7)^(l>>3)  (row&7 == l>>3).
  const int srow = (w << 3) + (l >> 3);
  const int ssw  = ((l & 7) ^ (l >> 3)) << 4;
  auto stageA = [&](int t, int h) {
    const char* src = partA(t) + (long)(blockM + h * 128 + srow) * ldAb
                      + ((t & 7) << 7) + ssw;
    char* dst = lds + ((t & 1) << 16) + (h << 14) + (w << 10);
    gload16(src, dst);
    gload16(src + (long)64 * ldAb, dst + 8192);
  };
  auto stageB = [&](int t, int h) {
    const char* src = partB(t) + (long)(blockN + h * 128 + srow) * ldBb
                      + ((t & 7) << 7) + ssw;
    char* dst = lds + ((t & 1) << 16) + 32768 + (h << 14) + (w << 10);
    gload16(src, dst);
    gload16(src + (long)64 * ldBb, dst + 8192);
  };

  f32x4 acc[8][4];
#pragma unroll
  for (int i = 0; i < 8; ++i)
#pragma unroll
    for (int j = 0; j < 4; ++j) acc[i][j] = (f32x4){0.f, 0.f, 0.f, 0.f};

  const int lr = l & 15;
  const int s0 = (((l >> 4) ^ (l & 7)) << 4);  // kh=0 slot byte (swizzled)
  const int s1 = s0 ^ 64;                      // kh=1

  // prologue: stage tiles 0 and 1 (8 loads each)
  stageA(0, 0); stageA(0, 1); stageB(0, 0); stageB(0, 1);
  stageA(1, 0); stageA(1, 1); stageB(1, 0); stageB(1, 1);
  VMW(8);  // tile 0 landed
  BAR();

  for (int t = 0; t < NT; ++t) {
    const char* aB = lds + ((t & 1) << 16) + (wm << 14);
    const char* bB = lds + ((t & 1) << 16) + 32768 + ((wn >> 1) << 14);
    const int br0 = (wn & 1) << 6;
    bf16x8 af[4][2], bn0[2][2], bn1[2][2];

    // ---- P1: quadrant (mh0, nh0)
#pragma unroll
    for (int mi = 0; mi < 4; ++mi) {
      const char* rp = aB + ((mi * 16 + lr) << 7);
      af[mi][0] = *(const bf16x8*)(rp + s0);
      af[mi][1] = *(const bf16x8*)(rp + s1);
    }
#pragma unroll
    for (int ni = 0; ni < 2; ++ni) {
      const char* rp = bB + ((br0 + ni * 16 + lr) << 7);
      bn0[ni][0] = *(const bf16x8*)(rp + s0);
      bn0[ni][1] = *(const bf16x8*)(rp + s1);
    }
    BAR(); LGKM0();
    __builtin_amdgcn_s_setprio(1);
#pragma unroll
    for (int mi = 0; mi < 4; ++mi)
#pragma unroll
      for (int ni = 0; ni < 2; ++ni)
#pragma unroll
        for (int kh = 0; kh < 2; ++kh)
          acc[mi][ni] = __builtin_amdgcn_mfma_f32_16x16x32_bf16(
              af[mi][kh], bn0[ni][kh], acc[mi][ni], 0, 0, 0);
    __builtin_amdgcn_s_setprio(0);
    BAR();

    // ---- P2: quadrant (mh0, nh1)
#pragma unroll
    for (int ni = 0; ni < 2; ++ni) {
      const char* rp = bB + ((br0 + 32 + ni * 16 + lr) << 7);
      bn1[ni][0] = *(const bf16x8*)(rp + s0);
      bn1[ni][1] = *(const bf16x8*)(rp + s1);
    }
    BAR(); LGKM0();
    __builtin_amdgcn_s_setprio(1);
#pragma unroll
    for (int mi = 0; mi < 4; ++mi)
#pragma unroll
      for (int ni = 0; ni < 2; ++ni)
#pragma unroll
        for (int kh = 0; kh < 2; ++kh)
          acc[mi][2 + ni] = __builtin_amdgcn_mfma_f32_16x16x32_bf16(
              af[mi][kh], bn1[ni][kh], acc[mi][2 + ni], 0, 0, 0);
    __builtin_amdgcn_s_setprio(0);
    BAR();

    // ---- P3: quadrant (mh1, nh0) + stage B(t+2) into dead B region
#pragma unroll
    for (int mi = 0; mi < 4; ++mi) {
      const char* rp = aB + ((64 + mi * 16 + lr) << 7);
      af[mi][0] = *(const bf16x8*)(rp + s0);
      af[mi][1] = *(const bf16x8*)(rp + s1);
    }
    if (t + 2 < NT) { stageB(t + 2, 0); stageB(t + 2, 1); }
    BAR(); LGKM0();
    __builtin_amdgcn_s_setprio(1);
#pragma unroll
    for (int mi = 0; mi < 4; ++mi)
#pragma unroll
      for (int ni = 0; ni < 2; ++ni)
#pragma unroll
        for (int kh = 0; kh < 2; ++kh)
          acc[4 + mi][ni] = __builtin_amdgcn_mfma_f32_16x16x32_bf16(
              af[mi][kh], bn0[ni][kh], acc[4 + mi][ni], 0, 0, 0);
    __builtin_amdgcn_s_setprio(0);
    BAR();

    // ---- P4: quadrant (mh1, nh1) + stage A(t+2) into dead A region
    if (t + 2 < NT) { stageA(t + 2, 0); stageA(t + 2, 1); }
    BAR(); LGKM0();
    __builtin_amdgcn_s_setprio(1);
#pragma unroll
    for (int mi = 0; mi < 4; ++mi)
#pragma unroll
      for (int ni = 0; ni < 2; ++ni)
#pragma unroll
        for (int kh = 0; kh < 2; ++kh)
          acc[4 + mi][2 + ni] = __builtin_amdgcn_mfma_f32_16x16x32_bf16(
              af[mi][kh], bn1[ni][kh], acc[4 + mi][2 + ni], 0, 0, 0);
    __builtin_amdgcn_s_setprio(0);
    if (t + 2 < NT) { VMW(8); } else { VMW(0); }
    BAR();
  }

  // ---- epilogue
  const long cb = (long)blockIdx.z * sC;
  const int m0 = (int)blockM + wm * 128 + ((l >> 4) << 2);
  const int n0 = (int)blockN + wn * 64 + lr;
#pragma unroll
  for (int mi = 0; mi < 8; ++mi)
#pragma unroll
    for (int ni = 0; ni < 4; ++ni)
#pragma unroll
      for (int r = 0; r < 4; ++r) {
        const int m = m0 + mi * 16 + r;
        const int n = n0 + ni * 16;
        const long idx = cb + (long)m * N + n;
        const float v = acc[mi][ni][r];
        if (EPI == 0) {
          outU[idx] = f2bf(sqrtf(v * v + 1e-8f));
        } else if (EPI == 1) {
          u16 h = f2bf(v);
          outU[idx] = h;
          outU2[idx] = f2bf(v - bf2f(h));
        } else if (EPI == 2) {
          outF[idx] = sqrtf(v * v + 1e-8f);
        } else if (EPI == 3) {
          outF[idx] = resid[idx] + v;
        } else if (EPI == 4) {
          outU[idx] = f2bf(gelu_tanh(v + bias[n]));
        } else {
          outF[idx] = resid[idx] + v + bias[n];
        }
      }
}

// ---------- launch ----------
extern "C" void kernel_launch(void* const* d_in, const int* in_sizes, int n_in,
                              void* d_out, int out_size, void* d_ws, size_t ws_size,
                              hipStream_t stream)
{
  const float* x   = (const float*)d_in[0];
  const float* g1  = (const float*)d_in[1];
  const float* be1 = (const float*)d_in[2];
  const float* Wv  = (const float*)d_in[3];
  const float* Ww  = (const float*)d_in[4];
  const float* g2  = (const float*)d_in[5];
  const float* be2 = (const float*)d_in[6];
  const float* W1  = (const float*)d_in[7];
  const float* b1  = (const float*)d_in[8];
  const float* W2  = (const float*)d_in[9];
  const float* b2  = (const float*)d_in[10];
  float* out = (float*)d_out;

  char* ws = (char*)d_ws;
  // B=64, T=E=512, H=2048, M=B*T=32768. Lifetimes allow heavy aliasing.
  u16* inp_hi  = (u16*)(ws);                 // [0,32M)   LN1 -> vx-GEMM
  u16* inp_lo  = (u16*)(ws + 33554432);      // [32,64M)  LN1 -> scores
  u16* proj_hi = (u16*)(ws + 67108864);      // [64,96M)  proj -> scores
  u16* proj_lo = (u16*)(ws + 100663296);     // [96,128M) proj -> scores
  float* scores= (float*)(ws + 134217728);   // [128,192M) scores -> softmax
  u16* attn    = proj_hi;                    // alias: written after proj dead
  u16* vx      = proj_lo;                    // alias: vx-GEMM runs post-softmax
  u16* h_in    = inp_hi;                     // alias: written after inp dead
  u16* h_mid   = (u16*)(ws + 33554432);      // [32,160M): all dead by MLP1
  char* wb = ws + 201326592;                 // weights live whole run
  u16* WvT  = (u16*)(wb);
  u16* WwTh = (u16*)(wb + 524288);
  u16* WwTl = (u16*)(wb + 1048576);
  u16* W1T  = (u16*)(wb + 1572864);
  u16* W2T  = (u16*)(wb + 3670016);
  // total ws used: ~207.1 MB

  // weight transposes (f32 -> bf16, K-contiguous for NT GEMM)
  transpose_split_kernel<<<dim3(16, 16), 256, 0, stream>>>(Wv, WvT, nullptr, 512, 512);
  transpose_split_kernel<<<dim3(16, 16), 256, 0, stream>>>(Ww, WwTh, WwTl, 512, 512);
  transpose_split_kernel<<<dim3(64, 16), 256, 0, stream>>>(W1, W1T, nullptr, 512, 2048);
  transpose_split_kernel<<<dim3(16, 64), 256, 0, stream>>>(W2, W2T, nullptr, 2048, 512);

  // LN1: x -> inp hi/lo
  ln_split_kernel<<<8192, 256, 0, stream>>>(x, g1, be1, inp_hi, inp_lo);

  // proj = inp@Ww, split 3-term via K-cat: [ih,il,ih] . [Wh,Wh,Wl], K'=1536
  gemm8<1><<<dim3(2, 128, 1), 512, 0, stream>>>(
      (const char*)inp_hi, (const char*)inp_lo, (const char*)inp_hi, (const char*)inp_hi,
      (const char*)WwTh, (const char*)WwTh, (const char*)WwTl, (const char*)WwTl,
      512, 24, 1024, 1024, 0, 0, 0,
      nullptr, proj_hi, proj_lo, nullptr, nullptr);

  // scores[b,i,j] = sqrt((proj_i . inp_j)^2+eps), split: [ph,ph,pl].[ih,il,ih]
  gemm8<2><<<dim3(2, 2, 64), 512, 0, stream>>>(
      (const char*)proj_hi, (const char*)proj_hi, (const char*)proj_lo, (const char*)proj_lo,
      (const char*)inp_hi, (const char*)inp_lo, (const char*)inp_hi, (const char*)inp_hi,
      512, 24, 1024, 1024, 524288, 524288, 262144,
      scores, nullptr, nullptr, nullptr, nullptr);

  // softmax rows -> attn bf16 (into dead proj_hi)
  softmax_kernel<<<8192, 256, 0, stream>>>(scores, attn);

  // vx = sqrt((inp@Wv)^2+eps) (into dead proj_lo)
  gemm8<0><<<dim3(2, 128, 1), 512, 0, stream>>>(
      (const char*)inp_hi, (const char*)inp_hi, (const char*)inp_hi, (const char*)inp_hi,
      (const char*)WvT, (const char*)WvT, (const char*)WvT, (const char*)WvT,
      512, 8, 1024, 1024, 0, 0, 0,
      nullptr, vx, nullptr, nullptr, nullptr);

  // x1 = x + attn@vx^T -> d_out (batched)
  gemm8<3><<<dim3(2, 2, 64), 512, 0, stream>>>(
      (const char*)attn, (const char*)attn, (const char*)attn, (const char*)attn,
      (const char*)vx, (const char*)vx, (const char*)vx, (const char*)vx,
      512, 8, 1024, 1024, 524288, 524288, 262144,
      out, nullptr, nullptr, x, nullptr);

  // LN2: x1 -> h_in (bf16 hi only)
  ln_split_kernel<<<8192, 256, 0, stream>>>(out, g2, be2, h_in, nullptr);

  // h_mid = gelu(h_in@W1 + b1)
  gemm8<4><<<dim3(8, 128, 1), 512, 0, stream>>>(
      (const char*)h_in, (const char*)h_in, (const char*)h_in, (const char*)h_in,
      (const char*)W1T, (const char*)W1T, (const char*)W1T, (const char*)W1T,
      2048, 8, 1024, 1024, 0, 0, 0,
      nullptr, h_mid, nullptr, nullptr, b1);

  // out = x1 + h_mid@W2 + b2  (K=2048 via 4 contiguous parts)
  gemm8<5><<<dim3(2, 128, 1), 512, 0, stream>>>(
      (const char*)h_mid, (const char*)h_mid + 1024, (const char*)h_mid + 2048, (const char*)h_mid + 3072,
      (const char*)W2T, (const char*)W2T + 1024, (const char*)W2T + 2048, (const char*)W2T + 3072,
      512, 32, 4096, 4096, 0, 0, 0,
      out, nullptr, nullptr, out, b2);
}

// Round 3
// 492.331 us; speedup vs baseline: 1.1767x; 1.0462x over previous
//
#include <hip/hip_runtime.h>

using bf16x8 = __attribute__((ext_vector_type(8))) short;
using f32x4  = __attribute__((ext_vector_type(4))) float;
using u16 = unsigned short;
using u32 = unsigned int;

// ---------- helpers ----------
__device__ __forceinline__ u16 f2bf(float f) {          // RNE float->bf16
  u32 u = __float_as_uint(f);
  u += 0x7fffu + ((u >> 16) & 1u);
  return (u16)(u >> 16);
}
__device__ __forceinline__ float bf2f(u16 h) {
  return __uint_as_float(((u32)h) << 16);
}
__device__ __forceinline__ uint4 pack8(const u16* h) {
  uint4 r;
  r.x = (u32)h[0] | ((u32)h[1] << 16);
  r.y = (u32)h[2] | ((u32)h[3] << 16);
  r.z = (u32)h[4] | ((u32)h[5] << 16);
  r.w = (u32)h[6] | ((u32)h[7] << 16);
  return r;
}
__device__ __forceinline__ float gelu_fast(float x) {   // == 0.5x(1+tanh(u)) exactly
  float u2 = 1.5957691216057308f * (x + 0.044715f * x * x * x);  // 2u
  return x / (1.0f + __expf(-u2));
}
__device__ __forceinline__ void gload16(const void* g, void* l) {
  __builtin_amdgcn_global_load_lds(
      (const __attribute__((address_space(1))) void*)g,
      (__attribute__((address_space(3))) void*)l, 16, 0, 0);
}

#define BAR() __builtin_amdgcn_s_barrier()
#define WLG(n)  do { asm volatile("s_waitcnt lgkmcnt(" #n ")" ::: "memory"); \
                     __builtin_amdgcn_sched_barrier(0); } while (0)
#define VMW(n)  do { asm volatile("s_waitcnt vmcnt(" #n ")" ::: "memory"); \
                     __builtin_amdgcn_sched_barrier(0); } while (0)

// ---------- weight transpose: [R,C] f32 -> [C,R] bf16 (hi, optional lo) ----------
__global__ __launch_bounds__(256) void transpose_split_kernel(
    const float* __restrict__ in, u16* __restrict__ outH, u16* __restrict__ outL,
    int R, int C)
{
  __shared__ float t[32][33];
  const int lx = threadIdx.x & 31, ly = threadIdx.x >> 5;
  const int c0 = blockIdx.x << 5, r0 = blockIdx.y << 5;
  for (int i = ly; i < 32; i += 8)
    t[i][lx] = in[(long)(r0 + i) * C + c0 + lx];
  __syncthreads();
  for (int i = ly; i < 32; i += 8) {
    float v = t[lx][i];
    long o = (long)(c0 + i) * R + r0 + lx;
    u16 h = f2bf(v);
    outH[o] = h;
    if (outL) outL[o] = f2bf(v - bf2f(h));
  }
}

// ---------- LayerNorm over rows of 512 f32, out bf16 hi (+ optional lo) ----------
__global__ __launch_bounds__(256) void ln_split_kernel(
    const float* __restrict__ x, const float* __restrict__ gamma,
    const float* __restrict__ beta, u16* __restrict__ outH, u16* __restrict__ outL)
{
  const int row  = (blockIdx.x << 2) + (threadIdx.x >> 6);
  const int lane = threadIdx.x & 63;
  const float* xr = x + (long)row * 512 + lane * 8;
  float v[8];
  *(float4*)&v[0] = *(const float4*)xr;
  *(float4*)&v[4] = *(const float4*)(xr + 4);
  float s = 0.f;
#pragma unroll
  for (int j = 0; j < 8; ++j) s += v[j];
#pragma unroll
  for (int o = 32; o; o >>= 1) s += __shfl_xor(s, o);
  const float mu = s * (1.0f / 512.0f);
  float q = 0.f;
#pragma unroll
  for (int j = 0; j < 8; ++j) { float d = v[j] - mu; q += d * d; }
#pragma unroll
  for (int o = 32; o; o >>= 1) q += __shfl_xor(q, o);
  const float rs = rsqrtf(q * (1.0f / 512.0f) + 1e-5f);
  float gv[8], bv[8];
  *(float4*)&gv[0] = *(const float4*)(gamma + lane * 8);
  *(float4*)&gv[4] = *(const float4*)(gamma + lane * 8 + 4);
  *(float4*)&bv[0] = *(const float4*)(beta + lane * 8);
  *(float4*)&bv[4] = *(const float4*)(beta + lane * 8 + 4);
  u16 hs[8], ls[8];
#pragma unroll
  for (int j = 0; j < 8; ++j) {
    float y = (v[j] - mu) * rs * gv[j] + bv[j];
    hs[j] = f2bf(y);
    ls[j] = f2bf(y - bf2f(hs[j]));
  }
  *(uint4*)(outH + (long)row * 512 + lane * 8) = pack8(hs);
  if (outL) *(uint4*)(outL + (long)row * 512 + lane * 8) = pack8(ls);
}

// ---------- row softmax over 512 f32 -> bf16 ----------
__global__ __launch_bounds__(256) void softmax_kernel(
    const float* __restrict__ scores, u16* __restrict__ attn)
{
  const int row  = (blockIdx.x << 2) + (threadIdx.x >> 6);
  const int lane = threadIdx.x & 63;
  const float* sr = scores + (long)row * 512 + lane * 8;
  float v[8];
  *(float4*)&v[0] = *(const float4*)sr;
  *(float4*)&v[4] = *(const float4*)(sr + 4);
  float m = v[0];
#pragma unroll
  for (int j = 1; j < 8; ++j) m = fmaxf(m, v[j]);
#pragma unroll
  for (int o = 32; o; o >>= 1) m = fmaxf(m, __shfl_xor(m, o));
  float e[8], s = 0.f;
#pragma unroll
  for (int j = 0; j < 8; ++j) { e[j] = __expf(v[j] - m); s += e[j]; }
#pragma unroll
  for (int o = 32; o; o >>= 1) s += __shfl_xor(s, o);
  const float inv = 1.0f / s;
  u16 h[4], h2[4];
#pragma unroll
  for (int j = 0; j < 4; ++j) h[j] = f2bf(e[j] * inv);
#pragma unroll
  for (int j = 0; j < 4; ++j) h2[j] = f2bf(e[4 + j] * inv);
  u16 hh[8] = {h[0], h[1], h[2], h[3], h2[0], h2[1], h2[2], h2[3]};
  *(uint4*)(attn + (long)row * 512 + lane * 8) = pack8(hh);
}

// ---------- 256x256 8-wave NT GEMM, BK=64, register-pipelined 4-phase ----------
// C[m,n] = sum_k A[m,k]*B[n,k]. K split into NT tiles of 64; tile t uses part
// pointer (t>>3) (enables hi/lo K-concatenation for split-precision GEMMs).
// Phases keyed by (m-half, k-half); each phase ISSUES next phase's ds_reads and
// waits the previous set with counted lgkmcnt -> LDS drain hides under MFMA.
// Staging: 2 LDS buffers (64KB each); during tile t stage t+1 into buf (t^1)&1
// (tile t-1 fully consumed before tile t starts -> region dead). One barrier
// per K-tile at the swap, after per-wave vmcnt(0) (loads issued ~3 phases ago).
// MFMA operands SWAPPED (mfma(B,A)): lane's 4 acc values = 4 consecutive N
// columns -> wide (8B/16B) epilogue stores.
// EPI: 0 bf16 sqrt(v^2+eps); 1 split hi/lo; 2 f32 sqrt(v^2+eps); 3 resid+v;
//      4 gelu(v+bias) bf16; 5 resid+v+bias.
template<int EPI>
__global__ __launch_bounds__(512, 2) void gemm8(
    const char* A0, const char* A1, const char* A2, const char* A3,
    const char* B0, const char* B1, const char* B2, const char* B3,
    int N, int NT, int ldAb, int ldBb,
    long sAb, long sBb, long sC,
    float* __restrict__ outF, u16* __restrict__ outU, u16* __restrict__ outU2,
    const float* __restrict__ resid, const float* __restrict__ bias)
{
  __shared__ __align__(16) char lds[131072];
  const int tid = threadIdx.x;
  const int w = tid >> 6, l = tid & 63;
  const int wm = w >> 2, wn = w & 3;
  const long blockM = (long)blockIdx.y * 256;
  const long blockN = (long)blockIdx.x * 256;
  const long za = (long)blockIdx.z * sAb;
  const long zb = (long)blockIdx.z * sBb;
  const char* a0 = A0 + za; const char* a1 = A1 + za;
  const char* a2 = A2 + za; const char* a3 = A3 + za;
  const char* b0 = B0 + zb; const char* b1 = B1 + zb;
  const char* b2 = B2 + zb; const char* b3 = B3 + zb;

  auto partA = [&](int t) { return t < 8 ? a0 : t < 16 ? a1 : t < 24 ? a2 : a3; };
  auto partB = [&](int t) { return t < 8 ? b0 : t < 16 ? b1 : t < 24 ? b2 : b3; };

  // staging: wave w covers rows w*8+(l>>3) and +64 of each 128-row half;
  // global source slot pre-swizzled: (l&7)^(l>>3) so LDS-linear dst ends up
  // XOR-swizzled (slot s of row r lives at s^(r&7)).
  const int srow = (w << 3) + (l >> 3);
  const int ssw  = ((l & 7) ^ (l >> 3)) << 4;
  auto stageA = [&](int t, int h) {
    const char* src = partA(t) + (long)(blockM + h * 128 + srow) * ldAb
                      + ((t & 7) << 7) + ssw;
    char* dst = lds + ((t & 1) << 16) + (h << 14) + (w << 10);
    gload16(src, dst);
    gload16(src + (long)64 * ldAb, dst + 8192);
  };
  auto stageB = [&](int t, int h) {
    const char* src = partB(t) + (long)(blockN + h * 128 + srow) * ldBb
                      + ((t & 7) << 7) + ssw;
    char* dst = lds + ((t & 1) << 16) + 32768 + (h << 14) + (w << 10);
    gload16(src, dst);
    gload16(src + (long)64 * ldBb, dst + 8192);
  };

  f32x4 acc[8][4];
#pragma unroll
  for (int i = 0; i < 8; ++i)
#pragma unroll
    for (int j = 0; j < 4; ++j) acc[i][j] = (f32x4){0.f, 0.f, 0.f, 0.f};

  const int lr = l & 15, kg = l >> 4;
  const int s0 = ((kg ^ (l & 7)) << 4);   // kh=0 swizzled slot byte
  const int s1 = s0 ^ 64;                 // kh=1

  bf16x8 af0[4], af1[4], bk0[4], bk1[4];

  auto readA = [&](bf16x8* d, const char* cur, int mh, int s) {
#pragma unroll
    for (int mi = 0; mi < 4; ++mi)
      d[mi] = *(const bf16x8*)(cur + (wm << 14) + (((mh << 6) + (mi << 4) + lr) << 7) + s);
  };
  auto readB = [&](bf16x8* d, const char* cur, int s) {
#pragma unroll
    for (int ni = 0; ni < 4; ++ni)
      d[ni] = *(const bf16x8*)(cur + 32768 + ((wn >> 1) << 14)
                               + ((((wn & 1) << 6) + (ni << 4) + lr) << 7) + s);
  };

  // prologue: stage tile 0 only; tile 1 staged during iteration 0.
  stageA(0, 0); stageA(0, 1); stageB(0, 0); stageB(0, 1);
  VMW(0); BAR();
  readA(af0, lds, 0, s0); readB(bk0, lds, s0);   // P1(0) operands

  for (int t = 0; t < NT; ++t) {
    const char* cur = lds + ((t & 1) << 16);
    // ---- P1: issue P2 ops (A[m0,k1], B[k1]); stage A(t+1); compute m0 x k0
    readA(af1, cur, 0, s1); readB(bk1, cur, s1);
    if (t + 1 < NT) { stageA(t + 1, 0); stageA(t + 1, 1); }
    WLG(8);
    __builtin_amdgcn_s_setprio(1);
#pragma unroll
    for (int mi = 0; mi < 4; ++mi)
#pragma unroll
      for (int ni = 0; ni < 4; ++ni)
        acc[mi][ni] = __builtin_amdgcn_mfma_f32_16x16x32_bf16(bk0[ni], af0[mi], acc[mi][ni], 0, 0, 0);
    __builtin_amdgcn_s_setprio(0);
    // ---- P2: issue P3 ops (A[m1,k1]); stage B(t+1); compute m0 x k1
    readA(af0, cur, 1, s1);
    if (t + 1 < NT) { stageB(t + 1, 0); stageB(t + 1, 1); }
    WLG(4);
    __builtin_amdgcn_s_setprio(1);
#pragma unroll
    for (int mi = 0; mi < 4; ++mi)
#pragma unroll
      for (int ni = 0; ni < 4; ++ni)
        acc[mi][ni] = __builtin_amdgcn_mfma_f32_16x16x32_bf16(bk1[ni], af1[mi], acc[mi][ni], 0, 0, 0);
    __builtin_amdgcn_s_setprio(0);
    // ---- P3: issue P4 ops (A[m1,k0]); compute m1 x k1
    readA(af1, cur, 1, s0);
    WLG(4);
    __builtin_amdgcn_s_setprio(1);
#pragma unroll
    for (int mi = 0; mi < 4; ++mi)
#pragma unroll
      for (int ni = 0; ni < 4; ++ni)
        acc[4 + mi][ni] = __builtin_amdgcn_mfma_f32_16x16x32_bf16(bk1[ni], af0[mi], acc[4 + mi][ni], 0, 0, 0);
    __builtin_amdgcn_s_setprio(0);
    // ---- P4: compute m1 x k0; swap
    WLG(0);
    __builtin_amdgcn_s_setprio(1);
#pragma unroll
    for (int mi = 0; mi < 4; ++mi)
#pragma unroll
      for (int ni = 0; ni < 4; ++ni)
        acc[4 + mi][ni] = __builtin_amdgcn_mfma_f32_16x16x32_bf16(bk0[ni], af1[mi], acc[4 + mi][ni], 0, 0, 0);
    __builtin_amdgcn_s_setprio(0);
    if (t + 1 < NT) {
      VMW(0);          // own t+1 staging landed (issued ~3 phases ago)
      BAR();           // publish across waves
      const char* nxt = lds + (((t + 1) & 1) << 16);
      readA(af0, nxt, 0, s0); readB(bk0, nxt, s0);   // next P1 operands
    }
  }

  // ---- epilogue (swapped layout): m = ..+lr, n = ..+kg*4+r  -> wide stores
  const long cb = (long)blockIdx.z * sC;
  const int m0 = (int)blockM + wm * 128 + lr;
  const int n0 = (int)blockN + wn * 64 + (kg << 2);
#pragma unroll
  for (int mi = 0; mi < 8; ++mi)
#pragma unroll
    for (int ni = 0; ni < 4; ++ni) {
      const int m = m0 + (mi << 4);
      const int n = n0 + (ni << 4);
      const long idx = cb + (long)m * N + n;
      f32x4 v = acc[mi][ni];
      if (EPI == 0) {
        union { u16 h[4]; uint2 u; } p;
#pragma unroll
        for (int r = 0; r < 4; ++r) p.h[r] = f2bf(sqrtf(v[r] * v[r] + 1e-8f));
        *(uint2*)(outU + idx) = p.u;
      } else if (EPI == 1) {
        union { u16 h[4]; uint2 u; } ph, pl;
#pragma unroll
        for (int r = 0; r < 4; ++r) {
          ph.h[r] = f2bf(v[r]);
          pl.h[r] = f2bf(v[r] - bf2f(ph.h[r]));
        }
        *(uint2*)(outU + idx) = ph.u;
        *(uint2*)(outU2 + idx) = pl.u;
      } else if (EPI == 2) {
        f32x4 o;
#pragma unroll
        for (int r = 0; r < 4; ++r) o[r] = sqrtf(v[r] * v[r] + 1e-8f);
        *(f32x4*)(outF + idx) = o;
      } else if (EPI == 3) {
        f32x4 rd = *(const f32x4*)(resid + idx);
#pragma unroll
        for (int r = 0; r < 4; ++r) rd[r] += v[r];
        *(f32x4*)(outF + idx) = rd;
      } else if (EPI == 4) {
        union { u16 h[4]; uint2 u; } p;
#pragma unroll
        for (int r = 0; r < 4; ++r) p.h[r] = f2bf(gelu_fast(v[r] + bias[n + r]));
        *(uint2*)(outU + idx) = p.u;
      } else {
        f32x4 rd = *(const f32x4*)(resid + idx);
        f32x4 bb = *(const f32x4*)(bias + n);
#pragma unroll
        for (int r = 0; r < 4; ++r) rd[r] += v[r] + bb[r];
        *(f32x4*)(outF + idx) = rd;
      }
    }
}

// ---------- launch ----------
extern "C" void kernel_launch(void* const* d_in, const int* in_sizes, int n_in,
                              void* d_out, int out_size, void* d_ws, size_t ws_size,
                              hipStream_t stream)
{
  const float* x   = (const float*)d_in[0];
  const float* g1  = (const float*)d_in[1];
  const float* be1 = (const float*)d_in[2];
  const float* Wv  = (const float*)d_in[3];
  const float* Ww  = (const float*)d_in[4];
  const float* g2  = (const float*)d_in[5];
  const float* be2 = (const float*)d_in[6];
  const float* W1  = (const float*)d_in[7];
  const float* b1  = (const float*)d_in[8];
  const float* W2  = (const float*)d_in[9];
  const float* b2  = (const float*)d_in[10];
  float* out = (float*)d_out;

  char* ws = (char*)d_ws;
  // B=64, T=E=512, H=2048, M=B*T=32768. Lifetimes allow heavy aliasing.
  u16* inp_hi  = (u16*)(ws);                 // [0,32M)   LN1 -> vx-GEMM
  u16* inp_lo  = (u16*)(ws + 33554432);      // [32,64M)  LN1 -> scores
  u16* proj_hi = (u16*)(ws + 67108864);      // [64,96M)  proj -> scores
  u16* proj_lo = (u16*)(ws + 100663296);     // [96,128M) proj -> scores
  float* scores= (float*)(ws + 134217728);   // [128,192M) scores -> softmax
  u16* attn    = proj_hi;                    // alias: written after proj dead
  u16* vx      = proj_lo;                    // alias: vx-GEMM runs post-softmax
  u16* h_in    = inp_hi;                     // alias: written after inp dead
  u16* h_mid   = (u16*)(ws + 33554432);      // [32,160M): all dead by MLP1
  char* wb = ws + 201326592;                 // weights live whole run
  u16* WvT  = (u16*)(wb);
  u16* WwTh = (u16*)(wb + 524288);
  u16* WwTl = (u16*)(wb + 1048576);
  u16* W1T  = (u16*)(wb + 1572864);
  u16* W2T  = (u16*)(wb + 3670016);
  // total ws used: ~207.1 MB

  // weight transposes (f32 -> bf16, K-contiguous for NT GEMM)
  transpose_split_kernel<<<dim3(16, 16), 256, 0, stream>>>(Wv, WvT, nullptr, 512, 512);
  transpose_split_kernel<<<dim3(16, 16), 256, 0, stream>>>(Ww, WwTh, WwTl, 512, 512);
  transpose_split_kernel<<<dim3(64, 16), 256, 0, stream>>>(W1, W1T, nullptr, 512, 2048);
  transpose_split_kernel<<<dim3(16, 64), 256, 0, stream>>>(W2, W2T, nullptr, 2048, 512);

  // LN1: x -> inp hi/lo
  ln_split_kernel<<<8192, 256, 0, stream>>>(x, g1, be1, inp_hi, inp_lo);

  // proj = inp@Ww, split 3-term via K-cat: [ih,il,ih] . [Wh,Wh,Wl], K'=1536
  gemm8<1><<<dim3(2, 128, 1), 512, 0, stream>>>(
      (const char*)inp_hi, (const char*)inp_lo, (const char*)inp_hi, (const char*)inp_hi,
      (const char*)WwTh, (const char*)WwTh, (const char*)WwTl, (const char*)WwTl,
      512, 24, 1024, 1024, 0, 0, 0,
      nullptr, proj_hi, proj_lo, nullptr, nullptr);

  // scores[b,i,j] = sqrt((proj_i . inp_j)^2+eps), split: [ph,ph,pl].[ih,il,ih]
  gemm8<2><<<dim3(2, 2, 64), 512, 0, stream>>>(
      (const char*)proj_hi, (const char*)proj_hi, (const char*)proj_lo, (const char*)proj_lo,
      (const char*)inp_hi, (const char*)inp_lo, (const char*)inp_hi, (const char*)inp_hi,
      512, 24, 1024, 1024, 524288, 524288, 262144,
      scores, nullptr, nullptr, nullptr, nullptr);

  // softmax rows -> attn bf16 (into dead proj_hi)
  softmax_kernel<<<8192, 256, 0, stream>>>(scores, attn);

  // vx = sqrt((inp@Wv)^2+eps) (into dead proj_lo)
  gemm8<0><<<dim3(2, 128, 1), 512, 0, stream>>>(
      (const char*)inp_hi, (const char*)inp_hi, (const char*)inp_hi, (const char*)inp_hi,
      (const char*)WvT, (const char*)WvT, (const char*)WvT, (const char*)WvT,
      512, 8, 1024, 1024, 0, 0, 0,
      nullptr, vx, nullptr, nullptr, nullptr);

  // x1 = x + attn@vx^T -> d_out (batched)
  gemm8<3><<<dim3(2, 2, 64), 512, 0, stream>>>(
      (const char*)attn, (const char*)attn, (const char*)attn, (const char*)attn,
      (const char*)vx, (const char*)vx, (const char*)vx, (const char*)vx,
      512, 8, 1024, 1024, 524288, 524288, 262144,
      out, nullptr, nullptr, x, nullptr);

  // LN2: x1 -> h_in (bf16 hi only)
  ln_split_kernel<<<8192, 256, 0, stream>>>(out, g2, be2, h_in, nullptr);

  // h_mid = gelu(h_in@W1 + b1)
  gemm8<4><<<dim3(8, 128, 1), 512, 0, stream>>>(
      (const char*)h_in, (const char*)h_in, (const char*)h_in, (const char*)h_in,
      (const char*)W1T, (const char*)W1T, (const char*)W1T, (const char*)W1T,
      2048, 8, 1024, 1024, 0, 0, 0,
      nullptr, h_mid, nullptr, nullptr, b1);

  // out = x1 + h_mid@W2 + b2  (K=2048 via 4 contiguous parts)
  gemm8<5><<<dim3(2, 128, 1), 512, 0, stream>>>(
      (const char*)h_mid, (const char*)h_mid + 1024, (const char*)h_mid + 2048, (const char*)h_mid + 3072,
      (const char*)W2T, (const char*)W2T + 1024, (const char*)W2T + 2048, (const char*)W2T + 3072,
      512, 32, 4096, 4096, 0, 0, 0,
      out, nullptr, nullptr, out, b2);
}

// Round 4
// 449.297 us; speedup vs baseline: 1.2894x; 1.0958x over previous
//
#include <hip/hip_runtime.h>

using bf16x8 = __attribute__((ext_vector_type(8))) short;
using f32x4  = __attribute__((ext_vector_type(4))) float;
using u16 = unsigned short;
using u32 = unsigned int;

// ---------- helpers ----------
__device__ __forceinline__ u16 f2bf(float f) {          // RNE float->bf16
  u32 u = __float_as_uint(f);
  u += 0x7fffu + ((u >> 16) & 1u);
  return (u16)(u >> 16);
}
__device__ __forceinline__ float bf2f(u16 h) {
  return __uint_as_float(((u32)h) << 16);
}
__device__ __forceinline__ uint4 pack8(const u16* h) {
  uint4 r;
  r.x = (u32)h[0] | ((u32)h[1] << 16);
  r.y = (u32)h[2] | ((u32)h[3] << 16);
  r.z = (u32)h[4] | ((u32)h[5] << 16);
  r.w = (u32)h[6] | ((u32)h[7] << 16);
  return r;
}
__device__ __forceinline__ float gelu_fast(float x) {   // == 0.5x(1+tanh(u)) exactly
  float u2 = 1.5957691216057308f * (x + 0.044715f * x * x * x);  // 2u
  return x / (1.0f + __expf(-u2));
}
__device__ __forceinline__ void gload16(const void* g, void* l) {
  __builtin_amdgcn_global_load_lds(
      (const __attribute__((address_space(1))) void*)g,
      (__attribute__((address_space(3))) void*)l, 16, 0, 0);
}

#define BAR()  do { __builtin_amdgcn_s_barrier(); \
                    __builtin_amdgcn_sched_barrier(0); } while (0)
#define WLG0() do { asm volatile("s_waitcnt lgkmcnt(0)" ::: "memory"); \
                    __builtin_amdgcn_sched_barrier(0); } while (0)
#define VMW(n) do { asm volatile("s_waitcnt vmcnt(" #n ")" ::: "memory"); \
                    __builtin_amdgcn_sched_barrier(0); } while (0)

// ---------- weight transpose: [R,C] f32 -> [C,R] bf16 (hi, optional lo) ----------
__global__ __launch_bounds__(256) void transpose_split_kernel(
    const float* __restrict__ in, u16* __restrict__ outH, u16* __restrict__ outL,
    int R, int C)
{
  __shared__ float t[32][33];
  const int lx = threadIdx.x & 31, ly = threadIdx.x >> 5;
  const int c0 = blockIdx.x << 5, r0 = blockIdx.y << 5;
  for (int i = ly; i < 32; i += 8)
    t[i][lx] = in[(long)(r0 + i) * C + c0 + lx];
  __syncthreads();
  for (int i = ly; i < 32; i += 8) {
    float v = t[lx][i];
    long o = (long)(c0 + i) * R + r0 + lx;
    u16 h = f2bf(v);
    outH[o] = h;
    if (outL) outL[o] = f2bf(v - bf2f(h));
  }
}

// ---------- LayerNorm over rows of 512 f32, out bf16 hi (+ optional lo) ----------
__global__ __launch_bounds__(256) void ln_split_kernel(
    const float* __restrict__ x, const float* __restrict__ gamma,
    const float* __restrict__ beta, u16* __restrict__ outH, u16* __restrict__ outL)
{
  const int row  = (blockIdx.x << 2) + (threadIdx.x >> 6);
  const int lane = threadIdx.x & 63;
  const float* xr = x + (long)row * 512 + lane * 8;
  float v[8];
  *(float4*)&v[0] = *(const float4*)xr;
  *(float4*)&v[4] = *(const float4*)(xr + 4);
  float s = 0.f;
#pragma unroll
  for (int j = 0; j < 8; ++j) s += v[j];
#pragma unroll
  for (int o = 32; o; o >>= 1) s += __shfl_xor(s, o);
  const float mu = s * (1.0f / 512.0f);
  float q = 0.f;
#pragma unroll
  for (int j = 0; j < 8; ++j) { float d = v[j] - mu; q += d * d; }
#pragma unroll
  for (int o = 32; o; o >>= 1) q += __shfl_xor(q, o);
  const float rs = rsqrtf(q * (1.0f / 512.0f) + 1e-5f);
  float gv[8], bv[8];
  *(float4*)&gv[0] = *(const float4*)(gamma + lane * 8);
  *(float4*)&gv[4] = *(const float4*)(gamma + lane * 8 + 4);
  *(float4*)&bv[0] = *(const float4*)(beta + lane * 8);
  *(float4*)&bv[4] = *(const float4*)(beta + lane * 8 + 4);
  u16 hs[8], ls[8];
#pragma unroll
  for (int j = 0; j < 8; ++j) {
    float y = (v[j] - mu) * rs * gv[j] + bv[j];
    hs[j] = f2bf(y);
    ls[j] = f2bf(y - bf2f(hs[j]));
  }
  *(uint4*)(outH + (long)row * 512 + lane * 8) = pack8(hs);
  if (outL) *(uint4*)(outL + (long)row * 512 + lane * 8) = pack8(ls);
}

// ---------- row softmax over 512 f32 -> bf16 ----------
__global__ __launch_bounds__(256) void softmax_kernel(
    const float* __restrict__ scores, u16* __restrict__ attn)
{
  const int row  = (blockIdx.x << 2) + (threadIdx.x >> 6);
  const int lane = threadIdx.x & 63;
  const float* sr = scores + (long)row * 512 + lane * 8;
  float v[8];
  *(float4*)&v[0] = *(const float4*)sr;
  *(float4*)&v[4] = *(const float4*)(sr + 4);
  float m = v[0];
#pragma unroll
  for (int j = 1; j < 8; ++j) m = fmaxf(m, v[j]);
#pragma unroll
  for (int o = 32; o; o >>= 1) m = fmaxf(m, __shfl_xor(m, o));
  float e[8], s = 0.f;
#pragma unroll
  for (int j = 0; j < 8; ++j) { e[j] = __expf(v[j] - m); s += e[j]; }
#pragma unroll
  for (int o = 32; o; o >>= 1) s += __shfl_xor(s, o);
  const float inv = 1.0f / s;
  u16 h[8];
#pragma unroll
  for (int j = 0; j < 8; ++j) h[j] = f2bf(e[j] * inv);
  *(uint4*)(attn + (long)row * 512 + lane * 8) = pack8(h);
}

// ---------- 256x256 8-wave NT GEMM, BK=64, quadrant-split counted-vmcnt ----------
// C[m,n] = sum_k A[m,k]*B[n,k]. K in NT tiles of 64; tile t uses part (t>>3)
// (hi/lo K-concatenation for split-precision GEMMs without materializing).
// LDS (128KB): A[d][q] 16KB regions at d*32768+q*16384; B same at +65536.
//   A-q holds global rows {q*64..+64} U {128+q*64..+64}  (both waves' quadrant q)
//   B-q holds global n-rows wn*64+q*32..+32 for all wn   (each wave's quadrant q)
// Phases per tile (compute quadrant Q(qm,qn), 16 MFMA each):
//   P1: vmcnt(4); BAR; read Aq0(8)+Bq0(4); stage A(t+1)q0; lgkm0; MFMA Q00
//   P2: vmcnt(4); BAR; read Bq1(4);        stage B(t+1)q0; lgkm0; MFMA Q01
//   P3: vmcnt(4); BAR; read Aq1(8);        stage B(t+1)q1; lgkm0; MFMA Q10
//   P4:                                    stage A(t+1)q1;        MFMA Q11
// Stage stream/tile = [Aq0,Bq0,Bq1,Aq1] into NON-current dbuf (prev content
// fully dead -> race-free any phase). Every consumption wait is a COUNTED
// vmcnt(4) (2 half-tiles stay in flight; 3-phase lead ~750cyc covers HBM
// latency); queue never drains. Cross-wave publication: own-vmcnt then BAR.
// Tail (t==NT-1, no stages issued): P2 vmcnt(2), P3 vmcnt(0).
// XCD-chunked swizzle: work = (flat%8)*(total/8)+flat/8 so the 8 bx-partners
// sharing an A-panel land on one XCD's L2 (all grids %8==0).
// MFMA operands swapped (mfma(B,A)): lane's acc quad = 4 consecutive N cols.
// EPI: 0 bf16 sqrt(v^2+eps); 1 split hi/lo; 2 f32 sqrt(v^2+eps); 3 resid+v;
//      4 gelu(v+bias) bf16; 5 resid+v+bias.
template<int EPI>
__global__ __launch_bounds__(512, 2) void gemm8(
    const char* A0, const char* A1, const char* A2, const char* A3,
    const char* B0, const char* B1, const char* B2, const char* B3,
    int N, int NT, int ldAb, int ldBb,
    long sAb, long sBb, long sC,
    float* __restrict__ outF, u16* __restrict__ outU, u16* __restrict__ outU2,
    const float* __restrict__ resid, const float* __restrict__ bias)
{
  __shared__ __align__(16) char lds[131072];
  const int tid = threadIdx.x;
  const int w = tid >> 6, l = tid & 63;
  const int wm = w >> 2, wn = w & 3;

  // XCD-chunked block swizzle (total %8 == 0 for all our launches)
  const int gx = gridDim.x, gy = gridDim.y;
  int flat = ((int)blockIdx.z * gy + (int)blockIdx.y) * gx + (int)blockIdx.x;
  const int total = gx * gy * (int)gridDim.z;
  flat = (flat & 7) * (total >> 3) + (flat >> 3);
  const int bx = flat % gx;
  int rem = flat / gx;
  const int by = rem % gy, bz = rem / gy;

  const long blockM = (long)by * 256;
  const long blockN = (long)bx * 256;
  const long za = (long)bz * sAb;
  const long zb = (long)bz * sBb;
  const char* a0p = A0 + za; const char* a1p = A1 + za;
  const char* a2p = A2 + za; const char* a3p = A3 + za;
  const char* b0p = B0 + zb; const char* b1p = B1 + zb;
  const char* b2p = B2 + zb; const char* b3p = B3 + zb;

  auto partA = [&](int t) { return t < 8 ? a0p : t < 16 ? a1p : t < 24 ? a2p : a3p; };
  auto partB = [&](int t) { return t < 8 ? b0p : t < 16 ? b1p : t < 24 ? b2p : b3p; };

  // staging: thread covers lds rows {w*8+(l>>3)} and +64 of a 128-row region;
  // global source slot pre-swizzled so LDS-linear dst = XOR-swizzled layout.
  const int srow = (w << 3) + (l >> 3);
  const int ssw  = ((l & 7) ^ (l >> 3)) << 4;
  auto stageA = [&](int t, int q) {
    const char* base = partA(t) + (((long)(t & 7)) << 7) + ssw;
    char* dst = lds + ((t & 1) << 15) + (q << 14) + (w << 10);
    gload16(base + (long)(blockM + q * 64 + srow) * ldAb, dst);
    gload16(base + (long)(blockM + 128 + q * 64 + srow) * ldAb, dst + 8192);
  };
  auto stageB = [&](int t, int q) {
    const char* base = partB(t) + (((long)(t & 7)) << 7) + ssw;
    char* dst = lds + 65536 + ((t & 1) << 15) + (q << 14) + (w << 10);
    const int v = srow;  // [0,64): n-group (v>>5), row-in-group (v&31)
    gload16(base + (long)(blockN + (v >> 5) * 64 + q * 32 + (v & 31)) * ldBb, dst);
    gload16(base + (long)(blockN + 128 + (v >> 5) * 64 + q * 32 + (v & 31)) * ldBb, dst + 8192);
  };

  f32x4 acc[8][4];
#pragma unroll
  for (int i = 0; i < 8; ++i)
#pragma unroll
    for (int j = 0; j < 4; ++j) acc[i][j] = (f32x4){0.f, 0.f, 0.f, 0.f};

  const int lr = l & 15, kg = l >> 4;
  const int s0 = ((kg ^ (l & 7)) << 4);   // kh=0 swizzled slot byte
  // kh=1 slot = s0 ^ 64

  bf16x8 af[4][2], b0[2][2], b1[2][2];

  auto readA = [&](int d, int qm) {
    const char* base = lds + (d << 15) + (qm << 14) + ((wm * 64 + lr) << 7) + s0;
#pragma unroll
    for (int mf = 0; mf < 4; ++mf) {
      af[mf][0] = *(const bf16x8*)(base + (mf << 11));
      af[mf][1] = *(const bf16x8*)(base + (mf << 11) + ((s0 ^ 64) - s0));
    }
  };
  auto readB = [&](int d, int qn, bf16x8 (*dst)[2]) {
    const char* base = lds + 65536 + (d << 15) + (qn << 14) + ((wn * 32 + lr) << 7) + s0;
#pragma unroll
    for (int nf = 0; nf < 2; ++nf) {
      dst[nf][0] = *(const bf16x8*)(base + (nf << 11));
      dst[nf][1] = *(const bf16x8*)(base + (nf << 11) + ((s0 ^ 64) - s0));
    }
  };

#define MFMA_Q(MB, NB, BARR)                                                  \
  do {                                                                        \
    __builtin_amdgcn_s_setprio(1);                                            \
    _Pragma("unroll")                                                         \
    for (int mf = 0; mf < 4; ++mf)                                            \
      _Pragma("unroll")                                                       \
      for (int nf = 0; nf < 2; ++nf)                                          \
        _Pragma("unroll")                                                     \
        for (int kh = 0; kh < 2; ++kh)                                        \
          acc[MB + mf][NB + nf] = __builtin_amdgcn_mfma_f32_16x16x32_bf16(    \
              BARR[nf][kh], af[mf][kh], acc[MB + mf][NB + nf], 0, 0, 0);      \
    __builtin_amdgcn_s_setprio(0);                                            \
  } while (0)

  // prologue: stage tile 0 in stream order [Aq0, Bq0, Bq1, Aq1]
  stageA(0, 0); stageB(0, 0); stageB(0, 1); stageA(0, 1);

  for (int t = 0; t < NT; ++t) {
    const int d = t & 1;
    const bool more = (t + 1 < NT);
    // ---- P1: consume A(t)q0 + B(t)q0
    VMW(4); BAR();
    readA(d, 0); readB(d, 0, b0);
    if (more) stageA(t + 1, 0);
    WLG0();
    MFMA_Q(0, 0, b0);
    // ---- P2: consume B(t)q1
    if (more) { VMW(4); } else { VMW(2); }
    BAR();
    readB(d, 1, b1);
    if (more) stageB(t + 1, 0);
    WLG0();
    MFMA_Q(0, 2, b1);
    // ---- P3: consume A(t)q1
    if (more) { VMW(4); } else { VMW(0); }
    BAR();
    readA(d, 1);
    if (more) stageB(t + 1, 1);
    WLG0();
    MFMA_Q(4, 0, b0);
    // ---- P4: no new LDS data
    if (more) stageA(t + 1, 1);
    MFMA_Q(4, 2, b1);
  }
#undef MFMA_Q

  // ---- epilogue (swapped layout): m = ..+lr, n = ..+kg*4+r -> wide stores
  const long cb = (long)bz * sC;
  const int m0 = (int)blockM + wm * 128 + lr;
  const int n0 = (int)blockN + wn * 64 + (kg << 2);
#pragma unroll
  for (int mi = 0; mi < 8; ++mi)
#pragma unroll
    for (int ni = 0; ni < 4; ++ni) {
      const int m = m0 + (mi << 4);
      const int n = n0 + (ni << 4);
      const long idx = cb + (long)m * N + n;
      f32x4 v = acc[mi][ni];
      if (EPI == 0) {
        union { u16 h[4]; uint2 u; } p;
#pragma unroll
        for (int r = 0; r < 4; ++r) p.h[r] = f2bf(sqrtf(v[r] * v[r] + 1e-8f));
        *(uint2*)(outU + idx) = p.u;
      } else if (EPI == 1) {
        union { u16 h[4]; uint2 u; } ph, pl;
#pragma unroll
        for (int r = 0; r < 4; ++r) {
          ph.h[r] = f2bf(v[r]);
          pl.h[r] = f2bf(v[r] - bf2f(ph.h[r]));
        }
        *(uint2*)(outU + idx) = ph.u;
        *(uint2*)(outU2 + idx) = pl.u;
      } else if (EPI == 2) {
        f32x4 o;
#pragma unroll
        for (int r = 0; r < 4; ++r) o[r] = sqrtf(v[r] * v[r] + 1e-8f);
        *(f32x4*)(outF + idx) = o;
      } else if (EPI == 3) {
        f32x4 rd = *(const f32x4*)(resid + idx);
#pragma unroll
        for (int r = 0; r < 4; ++r) rd[r] += v[r];
        *(f32x4*)(outF + idx) = rd;
      } else if (EPI == 4) {
        f32x4 bb = *(const f32x4*)(bias + n);
        union { u16 h[4]; uint2 u; } p;
#pragma unroll
        for (int r = 0; r < 4; ++r) p.h[r] = f2bf(gelu_fast(v[r] + bb[r]));
        *(uint2*)(outU + idx) = p.u;
      } else {
        f32x4 rd = *(const f32x4*)(resid + idx);
        f32x4 bb = *(const f32x4*)(bias + n);
#pragma unroll
        for (int r = 0; r < 4; ++r) rd[r] += v[r] + bb[r];
        *(f32x4*)(outF + idx) = rd;
      }
    }
}

// ---------- launch ----------
extern "C" void kernel_launch(void* const* d_in, const int* in_sizes, int n_in,
                              void* d_out, int out_size, void* d_ws, size_t ws_size,
                              hipStream_t stream)
{
  const float* x   = (const float*)d_in[0];
  const float* g1  = (const float*)d_in[1];
  const float* be1 = (const float*)d_in[2];
  const float* Wv  = (const float*)d_in[3];
  const float* Ww  = (const float*)d_in[4];
  const float* g2  = (const float*)d_in[5];
  const float* be2 = (const float*)d_in[6];
  const float* W1  = (const float*)d_in[7];
  const float* b1  = (const float*)d_in[8];
  const float* W2  = (const float*)d_in[9];
  const float* b2  = (const float*)d_in[10];
  float* out = (float*)d_out;

  char* ws = (char*)d_ws;
  // B=64, T=E=512, H=2048, M=B*T=32768. Lifetimes allow heavy aliasing.
  u16* inp_hi  = (u16*)(ws);                 // [0,32M)   LN1 -> vx-GEMM
  u16* inp_lo  = (u16*)(ws + 33554432);      // [32,64M)  LN1 -> scores
  u16* proj_hi = (u16*)(ws + 67108864);      // [64,96M)  proj -> scores
  u16* proj_lo = (u16*)(ws + 100663296);     // [96,128M) proj -> scores
  float* scores= (float*)(ws + 134217728);   // [128,192M) scores -> softmax
  u16* attn    = proj_hi;                    // alias: written after proj dead
  u16* vx      = proj_lo;                    // alias: vx-GEMM runs post-softmax
  u16* h_in    = inp_hi;                     // alias: written after inp dead
  u16* h_mid   = (u16*)(ws + 33554432);      // [32,160M): all dead by MLP1
  char* wb = ws + 201326592;                 // weights live whole run
  u16* WvT  = (u16*)(wb);
  u16* WwTh = (u16*)(wb + 524288);
  u16* WwTl = (u16*)(wb + 1048576);
  u16* W1T  = (u16*)(wb + 1572864);
  u16* W2T  = (u16*)(wb + 3670016);
  // total ws used: ~207.1 MB

  // weight transposes (f32 -> bf16, K-contiguous for NT GEMM)
  transpose_split_kernel<<<dim3(16, 16), 256, 0, stream>>>(Wv, WvT, nullptr, 512, 512);
  transpose_split_kernel<<<dim3(16, 16), 256, 0, stream>>>(Ww, WwTh, WwTl, 512, 512);
  transpose_split_kernel<<<dim3(64, 16), 256, 0, stream>>>(W1, W1T, nullptr, 512, 2048);
  transpose_split_kernel<<<dim3(16, 64), 256, 0, stream>>>(W2, W2T, nullptr, 2048, 512);

  // LN1: x -> inp hi/lo
  ln_split_kernel<<<8192, 256, 0, stream>>>(x, g1, be1, inp_hi, inp_lo);

  // proj = inp@Ww, split 3-term via K-cat: [ih,il,ih] . [Wh,Wh,Wl], K'=1536
  gemm8<1><<<dim3(2, 128, 1), 512, 0, stream>>>(
      (const char*)inp_hi, (const char*)inp_lo, (const char*)inp_hi, (const char*)inp_hi,
      (const char*)WwTh, (const char*)WwTh, (const char*)WwTl, (const char*)WwTl,
      512, 24, 1024, 1024, 0, 0, 0,
      nullptr, proj_hi, proj_lo, nullptr, nullptr);

  // scores[b,i,j] = sqrt((proj_i . inp_j)^2+eps), split: [ph,ph,pl].[ih,il,ih]
  gemm8<2><<<dim3(2, 2, 64), 512, 0, stream>>>(
      (const char*)proj_hi, (const char*)proj_hi, (const char*)proj_lo, (const char*)proj_lo,
      (const char*)inp_hi, (const char*)inp_lo, (const char*)inp_hi, (const char*)inp_hi,
      512, 24, 1024, 1024, 524288, 524288, 262144,
      scores, nullptr, nullptr, nullptr, nullptr);

  // softmax rows -> attn bf16 (into dead proj_hi)
  softmax_kernel<<<8192, 256, 0, stream>>>(scores, attn);

  // vx = sqrt((inp@Wv)^2+eps) (into dead proj_lo)
  gemm8<0><<<dim3(2, 128, 1), 512, 0, stream>>>(
      (const char*)inp_hi, (const char*)inp_hi, (const char*)inp_hi, (const char*)inp_hi,
      (const char*)WvT, (const char*)WvT, (const char*)WvT, (const char*)WvT,
      512, 8, 1024, 1024, 0, 0, 0,
      nullptr, vx, nullptr, nullptr, nullptr);

  // x1 = x + attn@vx^T -> d_out (batched)
  gemm8<3><<<dim3(2, 2, 64), 512, 0, stream>>>(
      (const char*)attn, (const char*)attn, (const char*)attn, (const char*)attn,
      (const char*)vx, (const char*)vx, (const char*)vx, (const char*)vx,
      512, 8, 1024, 1024, 524288, 524288, 262144,
      out, nullptr, nullptr, x, nullptr);

  // LN2: x1 -> h_in (bf16 hi only)
  ln_split_kernel<<<8192, 256, 0, stream>>>(out, g2, be2, h_in, nullptr);

  // h_mid = gelu(h_in@W1 + b1)
  gemm8<4><<<dim3(8, 128, 1), 512, 0, stream>>>(
      (const char*)h_in, (const char*)h_in, (const char*)h_in, (const char*)h_in,
      (const char*)W1T, (const char*)W1T, (const char*)W1T, (const char*)W1T,
      2048, 8, 1024, 1024, 0, 0, 0,
      nullptr, h_mid, nullptr, nullptr, b1);

  // out = x1 + h_mid@W2 + b2  (K=2048 via 4 contiguous parts)
  gemm8<5><<<dim3(2, 128, 1), 512, 0, stream>>>(
      (const char*)h_mid, (const char*)h_mid + 1024, (const char*)h_mid + 2048, (const char*)h_mid + 3072,
      (const char*)W2T, (const char*)W2T + 1024, (const char*)W2T + 2048, (const char*)W2T + 3072,
      512, 32, 4096, 4096, 0, 0, 0,
      out, nullptr, nullptr, out, b2);
}